// Round 2
// baseline (332.567 us; speedup 1.0000x reference)
//
#include <hip/hip_runtime.h>
#include <hip/hip_bf16.h>
#include <stdint.h>

#define BATCH 4
#define NPTS  1024
#define CIN   512
#define NS    32
#define P_TOT (BATCH*NPTS*NS)      /* 131072 */
#define K1    544                  /* 515 padded to 17*32 */
#define CO    512
#define RADIUS_F 0.05f
#define HMIN_F  (-0.02f)
#define HMAX_F  (0.04f)

typedef __attribute__((ext_vector_type(8))) short short8;
typedef __attribute__((ext_vector_type(4))) float f32x4;

__device__ __forceinline__ unsigned short f2bf(float f) {
  unsigned int x = __float_as_uint(f);
  x = x + 0x7fffu + ((x >> 16) & 1u);   // RNE
  return (unsigned short)(x >> 16);
}
__device__ __forceinline__ float bf2f(unsigned short u) {
  return __uint_as_float(((unsigned int)u) << 16);
}
__device__ __forceinline__ void load_lds16(const void* g, void* l) {
  __builtin_amdgcn_global_load_lds((const __attribute__((address_space(1))) void*)g,
                                   (__attribute__((address_space(3))) void*)l, 16, 0, 0);
}

// ---------------- cylinder query: idx + local coords into tail[p][0..31] ----
__global__ void cyl_query_kernel(const float* __restrict__ xyz,
                                 const float* __restrict__ rot,
                                 int* __restrict__ idxout,
                                 unsigned short* __restrict__ tail) {
  int bm = blockIdx.x;             // b*1024 + m
  int b = bm >> 10;
  int lane = threadIdx.x;          // 64 threads = 1 wave
  const float* ctr = xyz + (size_t)bm * 3;
  float cx = ctr[0], cy = ctr[1], cz = ctr[2];
  const float* R = rot + (size_t)bm * 9;
  float r00=R[0],r01=R[1],r02=R[2],r10=R[3],r11=R[4],r12=R[5],r20=R[6],r21=R[7],r22=R[8];
  __shared__ int sidx[32];
  int taken = 0;
  for (int base = 0; base < NPTS && taken < NS; base += 64) {
    int n = base + lane;
    const float* p = xyz + ((size_t)b * NPTS + n) * 3;
    float dx = p[0]-cx, dy = p[1]-cy, dz = p[2]-cz;
    float rx = dx*r00 + dy*r10 + dz*r20;
    float ry = dx*r01 + dy*r11 + dz*r21;
    float rz = dx*r02 + dy*r12 + dz*r22;
    bool ok = (ry*ry + rz*rz < RADIUS_F*RADIUS_F) && (rx > HMIN_F) && (rx < HMAX_F);
    unsigned long long bal = __ballot(ok);
    if (ok) {
      int slot = taken + __popcll(bal & ((1ull << lane) - 1ull));
      if (slot < NS) sidx[slot] = n;
    }
    taken += __popcll(bal);
  }
  __syncthreads();
  int filled = taken < NS ? taken : NS;
  if (lane < NS) {
    int nsel = (lane < filled) ? sidx[lane] : sidx[0];
    size_t p0 = (size_t)bm * NS + lane;
    idxout[p0] = nsel;
    const float* pn = xyz + ((size_t)b * NPTS + nsel) * 3;
    float dx = pn[0]-cx, dy = pn[1]-cy, dz = pn[2]-cz;
    const float inv = 1.0f / RADIUS_F;
    float rx = (dx*r00 + dy*r10 + dz*r20) * inv;
    float ry = (dx*r01 + dy*r11 + dz*r21) * inv;
    float rz = (dx*r02 + dy*r12 + dz*r22) * inv;
    unsigned short* row = tail + p0 * 32;
    row[0] = f2bf(rx); row[1] = f2bf(ry); row[2] = f2bf(rz);
    #pragma unroll
    for (int k = 3; k < 32; ++k) row[k] = 0;
  }
}

// ---------------- transpose feats (B,C,N) fp32 -> (B,N,C) bf16 --------------
__global__ void transpose_feats(const float* __restrict__ feats,
                                unsigned short* __restrict__ featsT) {
  __shared__ float tile[64][65];
  int b = blockIdx.z, cb = blockIdx.y, nb = blockIdx.x;
  int t = threadIdx.x, tr = t >> 6, tc = t & 63;
  #pragma unroll
  for (int j = 0; j < 16; ++j) {
    int c = cb*64 + j*4 + tr;
    tile[j*4+tr][tc] = feats[((size_t)b*CIN + c)*NPTS + nb*64 + tc];
  }
  __syncthreads();
  #pragma unroll
  for (int j = 0; j < 16; ++j) {
    int n = nb*64 + j*4 + tr;
    featsT[((size_t)b*NPTS + n)*CIN + cb*64 + tc] = f2bf(tile[tc][j*4+tr]);
  }
}

// ---------------- weight conversion -----------------------------------------
__global__ void build_w1(const float* __restrict__ W1, unsigned short* __restrict__ w1b) {
  int i = blockIdx.x*256 + threadIdx.x;
  if (i >= CO*K1) return;
  int o = i / K1, k = i % K1;
  float v = 0.f;
  if (k < 512) v = W1[o*515 + 3 + k];
  else if (k < 515) v = W1[o*515 + (k - 512)];
  w1b[i] = f2bf(v);
}
__global__ void build_w2(const float* __restrict__ W2, unsigned short* __restrict__ w2b) {
  int i = blockIdx.x*256 + threadIdx.x;
  if (i < CO*CIN) w2b[i] = f2bf(W2[i]);
}

// ---------------- GEMM1: gather-A (featsT via idx, tail) x W1^T -------------
// C[p][o] = sum_k A[p][k]*B[o][k]; also per-channel atomic sum/sumsq of acc.
__global__ __launch_bounds__(256) void gemm1_kernel(
    const unsigned short* __restrict__ fT,    // (B*N, 512) bf16
    const unsigned short* __restrict__ tail,  // (P, 32) bf16
    const int* __restrict__ idx,              // (P)
    const unsigned short* __restrict__ Bw,    // (512, 544) bf16
    unsigned short* __restrict__ C,           // (P, 512) bf16 (raw, pre-BN)
    float* __restrict__ sums)                 // [0..511]=sum, [512..1023]=sumsq
{
  __shared__ unsigned short As[128*32];
  __shared__ unsigned short Bs[128*32];
  int bx = blockIdx.x;
  int ob = bx & 3;
  size_t p0 = (size_t)(bx >> 2) * 128;
  int o0 = ob * 128;
  int t = threadIdx.x;
  int w = t >> 6, lane = t & 63;
  int wr = w >> 1, wc = w & 1;
  int l15 = lane & 15, l4 = lane >> 4;
  f32x4 acc[4][4];
  f32x4 zf = {0.f, 0.f, 0.f, 0.f};
  #pragma unroll
  for (int mi = 0; mi < 4; ++mi)
    #pragma unroll
    for (int ni = 0; ni < 4; ++ni) acc[mi][ni] = zf;

  int c0 = 2*w;
  int srow = lane >> 2;         // staged row within chunk (0..15)
  int scole = (lane & 3) * 8;   // element offset within 32-wide k-slab

  // per-chunk gather bases (row assignment is constant across the K loop)
  const unsigned short* abase[2];
  const unsigned short* tbase[2];
  #pragma unroll
  for (int cc = 0; cc < 2; ++cc) {
    int row = 16*(c0+cc) + srow;
    size_t p = p0 + row;
    int b = (int)(p >> 15);
    int n = idx[p];
    abase[cc] = fT + (((size_t)b << 10) + n) * (size_t)CIN + scole;
    tbase[cc] = tail + p * 32 + scole;
  }

  for (int k0 = 0; k0 < K1; k0 += 32) {
    #pragma unroll
    for (int cc = 0; cc < 2; ++cc) {
      int c = c0 + cc;
      const unsigned short* gA = (k0 < CIN) ? (abase[cc] + k0) : tbase[cc];
      load_lds16(gA, (char*)As + c*1024);
      int row = 16*c + srow;
      const unsigned short* gB = Bw + (size_t)(o0 + row)*K1 + k0 + scole;
      load_lds16(gB, (char*)Bs + c*1024);
    }
    __syncthreads();
    short8 af[4], bfr[4];
    #pragma unroll
    for (int mi = 0; mi < 4; ++mi)
      af[mi] = *(const short8*)(As + (wr*64 + mi*16 + l15)*32 + l4*8);
    #pragma unroll
    for (int ni = 0; ni < 4; ++ni)
      bfr[ni] = *(const short8*)(Bs + (wc*64 + ni*16 + l15)*32 + l4*8);
    #pragma unroll
    for (int mi = 0; mi < 4; ++mi)
      #pragma unroll
      for (int ni = 0; ni < 4; ++ni)
        acc[mi][ni] = __builtin_amdgcn_mfma_f32_16x16x32_bf16(af[mi], bfr[ni], acc[mi][ni], 0, 0, 0);
    __syncthreads();
  }

  // epilogue: per-channel stats (sum, sumsq) via shfl + atomics
  #pragma unroll
  for (int ni = 0; ni < 4; ++ni) {
    float s = 0.f, q = 0.f;
    #pragma unroll
    for (int mi = 0; mi < 4; ++mi)
      #pragma unroll
      for (int j = 0; j < 4; ++j) { float v = acc[mi][ni][j]; s += v; q += v*v; }
    s += __shfl_xor(s, 16); q += __shfl_xor(q, 16);
    s += __shfl_xor(s, 32); q += __shfl_xor(q, 32);
    if (l4 == 0) {
      int c = o0 + wc*64 + ni*16 + l15;
      atomicAdd(&sums[c], s);
      atomicAdd(&sums[512 + c], q);
    }
  }
  // C store (raw bf16)
  #pragma unroll
  for (int mi = 0; mi < 4; ++mi)
    #pragma unroll
    for (int ni = 0; ni < 4; ++ni)
      #pragma unroll
      for (int j = 0; j < 4; ++j) {
        size_t p = p0 + wr*64 + mi*16 + l4*4 + j;
        int o = o0 + wc*64 + ni*16 + l15;
        C[p*CO + o] = f2bf(acc[mi][ni][j]);
      }
}

__global__ void finalize_kernel(const float* __restrict__ sums,
                                const float* __restrict__ g,
                                const float* __restrict__ bia,
                                float* __restrict__ ss) {
  int c = blockIdx.x*256 + threadIdx.x;
  if (c >= 512) return;
  const float invN = 1.f / (float)P_TOT;
  float mean = sums[c] * invN;
  float var  = sums[512+c] * invN - mean*mean;
  float sc = g[c] * rsqrtf(var + 1e-5f);
  ss[c] = sc;
  ss[512+c] = bia[c] - mean*sc;
}

// ---------------- in-place normalize + relu (bf16) --------------------------
__global__ void norm_kernel(uint4* __restrict__ h, const float* __restrict__ ss) {
  size_t stride = (size_t)gridDim.x * blockDim.x;
  size_t total = (size_t)P_TOT * CO / 8;
  for (size_t i = (size_t)blockIdx.x*blockDim.x + threadIdx.x; i < total; i += stride) {
    int c = (int)((i*8) & 511);
    uint4 v = h[i];
    unsigned int wv[4] = {v.x, v.y, v.z, v.w};
    unsigned int rv[4];
    #pragma unroll
    for (int j = 0; j < 4; ++j) {
      float f0 = bf2f((unsigned short)(wv[j] & 0xffffu));
      float f1 = bf2f((unsigned short)(wv[j] >> 16));
      f0 = fmaxf(fmaf(f0, ss[c+2*j],   ss[512+c+2*j]),   0.f);
      f1 = fmaxf(fmaf(f1, ss[c+2*j+1], ss[512+c+2*j+1]), 0.f);
      rv[j] = (unsigned int)f2bf(f0) | ((unsigned int)f2bf(f1) << 16);
    }
    h[i] = make_uint4(rv[0], rv[1], rv[2], rv[3]);
  }
}

// ---------------- GEMM2: h1 x W2^T, fused stats + max/min pool over S -------
__global__ __launch_bounds__(256) void gemm2_kernel(
    const unsigned short* __restrict__ A,     // (P, 512) bf16 normalized
    const unsigned short* __restrict__ Bw,    // (512, 512) bf16
    float* __restrict__ sums,                 // [0..511]=sum, [512..1023]=sumsq
    float* __restrict__ pmax,                 // (4096, 512) f32
    float* __restrict__ pmin)                 // (4096, 512) f32
{
  __shared__ unsigned short As[128*32];
  __shared__ unsigned short Bs[128*32];
  int bx = blockIdx.x;
  int ob = bx & 3;
  size_t p0 = (size_t)(bx >> 2) * 128;
  int o0 = ob * 128;
  int t = threadIdx.x;
  int w = t >> 6, lane = t & 63;
  int wr = w >> 1, wc = w & 1;
  int l15 = lane & 15, l4 = lane >> 4;
  f32x4 acc[4][4];
  f32x4 zf = {0.f, 0.f, 0.f, 0.f};
  #pragma unroll
  for (int mi = 0; mi < 4; ++mi)
    #pragma unroll
    for (int ni = 0; ni < 4; ++ni) acc[mi][ni] = zf;

  int c0 = 2*w;
  int srow = lane >> 2;
  int scole = (lane & 3) * 8;

  for (int k0 = 0; k0 < CIN; k0 += 32) {
    #pragma unroll
    for (int cc = 0; cc < 2; ++cc) {
      int c = c0 + cc;
      int row = 16*c + srow;
      const unsigned short* gA = A + (p0 + row)*(size_t)CIN + k0 + scole;
      load_lds16(gA, (char*)As + c*1024);
      const unsigned short* gB = Bw + (size_t)(o0 + row)*CIN + k0 + scole;
      load_lds16(gB, (char*)Bs + c*1024);
    }
    __syncthreads();
    short8 af[4], bfr[4];
    #pragma unroll
    for (int mi = 0; mi < 4; ++mi)
      af[mi] = *(const short8*)(As + (wr*64 + mi*16 + l15)*32 + l4*8);
    #pragma unroll
    for (int ni = 0; ni < 4; ++ni)
      bfr[ni] = *(const short8*)(Bs + (wc*64 + ni*16 + l15)*32 + l4*8);
    #pragma unroll
    for (int mi = 0; mi < 4; ++mi)
      #pragma unroll
      for (int ni = 0; ni < 4; ++ni)
        acc[mi][ni] = __builtin_amdgcn_mfma_f32_16x16x32_bf16(af[mi], bfr[ni], acc[mi][ni], 0, 0, 0);
    __syncthreads();
  }

  // stats
  #pragma unroll
  for (int ni = 0; ni < 4; ++ni) {
    float s = 0.f, q = 0.f;
    #pragma unroll
    for (int mi = 0; mi < 4; ++mi)
      #pragma unroll
      for (int j = 0; j < 4; ++j) { float v = acc[mi][ni][j]; s += v; q += v*v; }
    s += __shfl_xor(s, 16); q += __shfl_xor(q, 16);
    s += __shfl_xor(s, 32); q += __shfl_xor(q, 32);
    if (l4 == 0) {
      int c = o0 + wc*64 + ni*16 + l15;
      atomicAdd(&sums[c], s);
      atomicAdd(&sums[512 + c], q);
    }
  }
  // max/min pool over S=32 (each 32-row group = one (b,m) seed)
  #pragma unroll
  for (int ni = 0; ni < 4; ++ni) {
    #pragma unroll
    for (int h = 0; h < 2; ++h) {
      float mx = -3.4e38f, mn = 3.4e38f;
      #pragma unroll
      for (int mi = 2*h; mi < 2*h + 2; ++mi)
        #pragma unroll
        for (int j = 0; j < 4; ++j) {
          float v = acc[mi][ni][j];
          mx = fmaxf(mx, v); mn = fminf(mn, v);
        }
      mx = fmaxf(mx, __shfl_xor(mx, 16)); mn = fminf(mn, __shfl_xor(mn, 16));
      mx = fmaxf(mx, __shfl_xor(mx, 32)); mn = fminf(mn, __shfl_xor(mn, 32));
      if (l4 == 0) {
        size_t bm = (p0 >> 5) + 2*wr + h;
        int o = o0 + wc*64 + ni*16 + l15;
        pmax[bm*512 + o] = mx;
        pmin[bm*512 + o] = mn;
      }
    }
  }
}

// ---------------- final: affine+relu on pooled, transpose to (B,512,M) ------
__global__ void final_transpose(const float* __restrict__ pmax,
                                const float* __restrict__ pmin,
                                const float* __restrict__ ss,
                                float* __restrict__ out) {
  __shared__ float tile[64][65];
  int b = blockIdx.z, ob = blockIdx.y, mb = blockIdx.x;
  int t = threadIdx.x, tr = t >> 6, tc = t & 63;
  #pragma unroll
  for (int j = 0; j < 16; ++j) {
    int m = mb*64 + j*4 + tr;
    int o = ob*64 + tc;
    float sc = ss[o], sh = ss[512+o];
    size_t pi = (((size_t)b << 10) + m)*512 + o;
    float v = (sc >= 0.f) ? pmax[pi] : pmin[pi];
    tile[j*4+tr][tc] = fmaxf(fmaf(v, sc, sh), 0.f);
  }
  __syncthreads();
  #pragma unroll
  for (int j = 0; j < 16; ++j) {
    int o = ob*64 + j*4 + tr;
    out[((size_t)b*512 + o)*1024 + mb*64 + tc] = tile[tc][j*4+tr];
  }
}

extern "C" void kernel_launch(void* const* d_in, const int* in_sizes, int n_in,
                              void* d_out, int out_size, void* d_ws, size_t ws_size,
                              hipStream_t stream) {
  const float* xyz   = (const float*)d_in[0];
  const float* feats = (const float*)d_in[1];
  const float* rot   = (const float*)d_in[2];
  const float* W1    = (const float*)d_in[3];
  const float* g1    = (const float*)d_in[4];
  const float* b1    = (const float*)d_in[5];
  const float* W2    = (const float*)d_in[6];
  const float* g2    = (const float*)d_in[7];
  const float* b2    = (const float*)d_in[8];
  float* out = (float*)d_out;
  char* wsb = (char*)d_ws;

  const size_t OFF_IDX    = 0;                                          // 0.5 MB
  const size_t OFF_TAIL   = OFF_IDX    + (size_t)P_TOT*4;               // 8.4 MB
  const size_t OFF_FEATST = OFF_TAIL   + (size_t)P_TOT*32*2;            // 4.2 MB
  const size_t OFF_W1B    = OFF_FEATST + (size_t)BATCH*NPTS*CIN*2;      // 0.56 MB
  const size_t OFF_W2B    = OFF_W1B    + (size_t)CO*K1*2;               // 0.52 MB
  const size_t OFF_STATS  = OFF_W2B    + (size_t)CO*CIN*2;              // 16 KB
  const size_t OFF_PMAX   = OFF_STATS  + 16384;                         // 8.4 MB
  const size_t OFF_PMIN   = OFF_PMAX   + (size_t)BATCH*NPTS*CO*4;       // 8.4 MB
  const size_t OFF_H1     = OFF_PMIN   + (size_t)BATCH*NPTS*CO*4;       // 134.2 MB
  const size_t WS_NEED    = OFF_H1     + (size_t)P_TOT*CO*2;            // ~158 MiB

  // Diagnostic guard: if the workspace is too small, launch nothing (clean
  // absmax failure instead of a GPU memory fault).
  if (ws_size < WS_NEED) return;

  int* idx             = (int*)(wsb + OFF_IDX);
  unsigned short* tail = (unsigned short*)(wsb + OFF_TAIL);
  unsigned short* fT   = (unsigned short*)(wsb + OFF_FEATST);
  unsigned short* w1b  = (unsigned short*)(wsb + OFF_W1B);
  unsigned short* w2b  = (unsigned short*)(wsb + OFF_W2B);
  float* stats         = (float*)(wsb + OFF_STATS);
  float* sums1 = stats;            // [0..1023]
  float* ss1   = stats + 1024;     // [1024..2047]
  float* sums2 = stats + 2048;
  float* ss2   = stats + 3072;
  float* pmax          = (float*)(wsb + OFF_PMAX);
  float* pmin          = (float*)(wsb + OFF_PMIN);
  unsigned short* h1   = (unsigned short*)(wsb + OFF_H1);

  hipMemsetAsync(stats, 0, 16384, stream);

  transpose_feats<<<dim3(NPTS/64, CIN/64, BATCH), 256, 0, stream>>>(feats, fT);
  cyl_query_kernel<<<BATCH*NPTS, 64, 0, stream>>>(xyz, rot, idx, tail);
  build_w1<<<(CO*K1 + 255)/256, 256, 0, stream>>>(W1, w1b);
  build_w2<<<(CO*CIN + 255)/256, 256, 0, stream>>>(W2, w2b);

  gemm1_kernel<<<(P_TOT/128)*4, 256, 0, stream>>>(fT, tail, idx, w1b, h1, sums1);
  finalize_kernel<<<2, 256, 0, stream>>>(sums1, g1, b1, ss1);
  norm_kernel<<<4096, 256, 0, stream>>>((uint4*)h1, ss1);

  gemm2_kernel<<<(P_TOT/128)*4, 256, 0, stream>>>(h1, w2b, sums2, pmax, pmin);
  finalize_kernel<<<2, 256, 0, stream>>>(sums2, g2, b2, ss2);

  final_transpose<<<dim3(NPTS/64, CO/64, BATCH), 256, 0, stream>>>(pmax, pmin, ss2, out);
}